// Round 1
// baseline (20.518 us; speedup 1.0000x reference)
//
#include <hip/hip_runtime.h>

// Reference collapses: softmax over singleton axis => weights == 1.
// out[b, g*M+m, h, w] = sum_{7x7 window} v[b,g,m,:,:],  v = grouped 1x1 conv(x, Wv).
// Separable box sum; horizontal pass commutes with the 1x1 conv, so:
//   hp[c8] = 7-tap horizontal box of x[channel c8]
//   out[m] = sum_c8 Wv[m][c8] * (7-tap vertical box of hp[c8])

#define TH   16          // output rows per block
#define HALO 3
#define HPR  (TH + 6)    // 22 rows incl. halo
#define WID  64
#define HGT  64
#define NG   8           // groups
#define NM   8           // mid channels per group
#define NC   8           // input channels per group

__global__ __launch_bounds__(256)
void mhsa_boxsum_kernel(const float* __restrict__ x,
                        const float* __restrict__ Wv,
                        float* __restrict__ out) {
    __shared__ float hp[NC * HPR * WID];   // 8*22*64 floats = 45056 B
    __shared__ float wv_s[NM * NC];        // 64 floats

    const int bg   = blockIdx.y;           // b*G + g  (0..63)
    const int tile = blockIdx.x;           // 0..3
    const int r0   = tile * TH;
    const int tid  = (int)threadIdx.x;
    const int lane = tid & 63;
    const int wave = tid >> 6;

    // Wv[g][m][c8] for this block's group
    const int g = bg & (NG - 1);
    if (tid < NM * NC) wv_s[tid] = Wv[g * (NM * NC) + tid];

    // x channel index: b*Cin + g*NC + c8 == bg*NC + c8
    const float* xbase = x + (size_t)bg * NC * HGT * WID;

    // ---- Phase 1: horizontal 7-tap box sum of x into LDS (wave per row) ----
    for (int t = wave; t < NC * HPR; t += 4) {
        const int c8 = t / HPR;
        const int r  = t - c8 * HPR;
        const int gr = r0 - HALO + r;
        float v = 0.0f;
        if (gr >= 0 && gr < HGT)
            v = xbase[((size_t)c8 * HGT + gr) * WID + lane];
        float s = v, tmp;
        tmp = __shfl_up(v, 1);   s += (lane >= 1)  ? tmp : 0.0f;
        tmp = __shfl_up(v, 2);   s += (lane >= 2)  ? tmp : 0.0f;
        tmp = __shfl_up(v, 3);   s += (lane >= 3)  ? tmp : 0.0f;
        tmp = __shfl_down(v, 1); s += (lane < 63)  ? tmp : 0.0f;
        tmp = __shfl_down(v, 2); s += (lane < 62)  ? tmp : 0.0f;
        tmp = __shfl_down(v, 3); s += (lane < 61)  ? tmp : 0.0f;
        hp[(c8 * HPR + r) * WID + lane] = s;
    }
    __syncthreads();

    // ---- Phase 2: vertical 7-tap + 1x1 conv (Wv) + store ----
    float w[NM * NC];
    #pragma unroll
    for (int i = 0; i < NM * NC; ++i) w[i] = wv_s[i];

    // out channel index: b*Cout + g*NM + m == bg*NM + m
    float* obase = out + (size_t)bg * NM * HGT * WID;
    const int c = lane;

    #pragma unroll
    for (int rsub = 0; rsub < TH / 4; ++rsub) {
        const int r = wave * (TH / 4) + rsub;   // 0..15
        float vb[NC];
        #pragma unroll
        for (int c8 = 0; c8 < NC; ++c8) {
            float a = 0.0f;
            #pragma unroll
            for (int dr = 0; dr < 7; ++dr)
                a += hp[(c8 * HPR + r + dr) * WID + c];
            vb[c8] = a;
        }
        #pragma unroll
        for (int m = 0; m < NM; ++m) {
            float o = 0.0f;
            #pragma unroll
            for (int c8 = 0; c8 < NC; ++c8)
                o += w[m * NC + c8] * vb[c8];
            obase[((size_t)m * HGT + (r0 + r)) * WID + c] = o;
        }
    }
}

extern "C" void kernel_launch(void* const* d_in, const int* in_sizes, int n_in,
                              void* d_out, int out_size, void* d_ws, size_t ws_size,
                              hipStream_t stream) {
    const float* x  = (const float*)d_in[0];
    // d_in[1] = Wq, d_in[2] = Wk  -- dead (softmax over singleton axis == 1)
    const float* Wv = (const float*)d_in[3];
    float* out = (float*)d_out;

    dim3 grid(HGT / TH, 8 * NG);   // (row tiles, B*G)
    dim3 block(256);
    mhsa_boxsum_kernel<<<grid, block, 0, stream>>>(x, Wv, out);
}

// Round 2
// 15.206 us; speedup vs baseline: 1.3494x; 1.3494x over previous
//
#include <hip/hip_runtime.h>

// Reference collapses: softmax over singleton axis => weights == 1.
// out[b, g*M+m, h, w] = sum_{7x7 window} v[b,g,m,:,:],  v = grouped 1x1 conv(x, Wv).
// Separable box sum; horizontal pass commutes with the 1x1 conv:
//   hp[c8] = 7-tap horizontal box of x[channel c8]
//   out[m] = sum_c8 Wv[m][c8] * (7-tap vertical box of hp[c8])
//
// R2: TH 16->4 (1024 blocks, 4/CU, 16 waves/CU co-resident) to fix the
// 1-wave/SIMD latency bind; XCD-aware swizzle keeps all tiles of one (b,g)
// on one XCD so halo re-reads are L2-hits.

#define TH   4           // output rows per block
#define HALO 3
#define HPR  (TH + 6)    // 10 rows incl. halo
#define WID  64
#define HGT  64
#define NG   8           // groups
#define NM   8           // mid channels per group
#define NC   8           // input channels per group
#define NTILE (HGT / TH) // 16 row tiles
#define NBG  64          // B*G

__global__ __launch_bounds__(256)
void mhsa_boxsum_kernel(const float* __restrict__ x,
                        const float* __restrict__ Wv,
                        float* __restrict__ out) {
    __shared__ float hp[NC * HPR * WID];   // 8*10*64 floats = 20480 B
    __shared__ float wv_s[NM * NC];        // 64 floats

    // ---- bijective XCD-aware decode: 1024 blocks, 8 XCDs, 128 blocks/XCD.
    // All 16 tiles of a (b,g) land on the same XCD -> halo rows L2-hit.
    const int lb   = (int)blockIdx.x;      // 0..1023
    const int xcd  = lb & 7;
    const int ix   = lb >> 3;              // 0..127
    const int bg   = xcd * 8 + (ix >> 4);  // 0..63
    const int tile = ix & 15;              // 0..15
    const int r0   = tile * TH;

    const int tid  = (int)threadIdx.x;
    const int lane = tid & 63;
    const int wave = tid >> 6;

    const int g = bg & (NG - 1);
    if (tid < NM * NC) wv_s[tid] = Wv[g * (NM * NC) + tid];

    // x channel base: b*Cin + g*NC == bg*NC
    const float* xbase = x + (size_t)bg * NC * HGT * WID;

    // ---- Phase 1: horizontal 7-tap box sum into LDS (wave per row) ----
    for (int t = wave; t < NC * HPR; t += 4) {
        const int c8 = t / HPR;
        const int r  = t - c8 * HPR;
        const int gr = r0 - HALO + r;
        float v = 0.0f;
        if (gr >= 0 && gr < HGT)
            v = xbase[((size_t)c8 * HGT + gr) * WID + lane];
        float s = v, tmp;
        tmp = __shfl_up(v, 1);   s += (lane >= 1)  ? tmp : 0.0f;
        tmp = __shfl_up(v, 2);   s += (lane >= 2)  ? tmp : 0.0f;
        tmp = __shfl_up(v, 3);   s += (lane >= 3)  ? tmp : 0.0f;
        tmp = __shfl_down(v, 1); s += (lane < 63)  ? tmp : 0.0f;
        tmp = __shfl_down(v, 2); s += (lane < 62)  ? tmp : 0.0f;
        tmp = __shfl_down(v, 3); s += (lane < 61)  ? tmp : 0.0f;
        hp[(c8 * HPR + r) * WID + lane] = s;
    }
    __syncthreads();

    // ---- Phase 2: vertical 7-tap + 1x1 conv (Wv) + store; 1 pixel/thread ----
    float w[NM * NC];
    #pragma unroll
    for (int i = 0; i < NM * NC; ++i) w[i] = wv_s[i];

    const int r = wave;          // 0..3
    const int c = lane;          // 0..63

    float vb[NC];
    #pragma unroll
    for (int c8 = 0; c8 < NC; ++c8) {
        float a = 0.0f;
        #pragma unroll
        for (int dr = 0; dr < 7; ++dr)
            a += hp[(c8 * HPR + r + dr) * WID + c];
        vb[c8] = a;
    }

    float* obase = out + (size_t)bg * NM * HGT * WID;
    #pragma unroll
    for (int m = 0; m < NM; ++m) {
        float o = 0.0f;
        #pragma unroll
        for (int c8 = 0; c8 < NC; ++c8)
            o += w[m * NC + c8] * vb[c8];
        obase[((size_t)m * HGT + (r0 + r)) * WID + c] = o;
    }
}

extern "C" void kernel_launch(void* const* d_in, const int* in_sizes, int n_in,
                              void* d_out, int out_size, void* d_ws, size_t ws_size,
                              hipStream_t stream) {
    const float* x  = (const float*)d_in[0];
    // d_in[1] = Wq, d_in[2] = Wk  -- dead (softmax over singleton axis == 1)
    const float* Wv = (const float*)d_in[3];
    float* out = (float*)d_out;

    dim3 grid(NTILE * NBG);   // 1024 blocks
    dim3 block(256);
    mhsa_boxsum_kernel<<<grid, block, 0, stream>>>(x, Wv, out);
}

// Round 3
// 10.542 us; speedup vs baseline: 1.9464x; 1.4424x over previous
//
#include <hip/hip_runtime.h>

// Reference collapses: softmax over singleton axis => weights == 1.
// out[b, g*M+m, h, w] = sum_{7x7 window} v[b,g,m,:,:],  v = grouped 1x1 conv(x, Wv).
// Separable box sum; horizontal pass commutes with the 1x1 conv:
//   hp[c8] = 7-tap horizontal box of x[channel c8]
//   out[m] = sum_c8 Wv[m][c8] * (7-tap vertical box of hp[c8])
//
// R3: phase-1 loads vectorized to float4 (16 lanes/row, 4 w per lane):
// 4x fewer VMEM instructions, 6 shfl + 12 add per FOUR outputs (running sum),
// ds_write_b128 staging. Phase 2 and grid (1024 blocks, 16 waves/CU) unchanged.

#define TH   4           // output rows per block
#define HALO 3
#define HPR  (TH + 6)    // 10 rows incl. halo
#define WID  64
#define HGT  64
#define NG   8
#define NM   8
#define NC   8
#define NTILE (HGT / TH) // 16
#define NBG  64          // B*G

typedef float f4 __attribute__((ext_vector_type(4)));

__global__ __launch_bounds__(256)
void mhsa_boxsum_kernel(const float* __restrict__ x,
                        const float* __restrict__ Wv,
                        float* __restrict__ out) {
    __shared__ float hp[NC * HPR * WID];   // 8*10*64 floats = 20480 B
    __shared__ float wv_s[NM * NC];

    // bijective XCD-aware decode: all 16 tiles of a (b,g) on one XCD
    const int lb   = (int)blockIdx.x;      // 0..1023
    const int xcd  = lb & 7;
    const int ix   = lb >> 3;              // 0..127
    const int bg   = xcd * 8 + (ix >> 4);  // 0..63
    const int tile = ix & 15;              // 0..15
    const int r0   = tile * TH;

    const int tid  = (int)threadIdx.x;
    const int lane = tid & 63;
    const int wave = tid >> 6;
    const int q    = lane & 15;            // w-quad within row (w = 4q+j)
    const int sub  = lane >> 4;            // which flat-row of 4 this group owns

    const int g = bg & (NG - 1);
    if (tid < NM * NC) wv_s[tid] = Wv[g * (NM * NC) + tid];

    const float* xbase = x + (size_t)bg * NC * HGT * WID;

    // ---- Phase 1: horizontal 7-tap box, float4 per lane ----
    // 80 flat rows (8 ch x 10 rows); 16 flat-rows per iter (4 waves x 4 groups)
    #pragma unroll
    for (int it = 0; it < 5; ++it) {
        const int f  = it * 16 + wave * 4 + sub;   // 0..79
        const int c8 = (f * 205) >> 11;            // f / 10 (exact for f < 80)
        const int r  = f - c8 * 10;
        const int gr = r0 - HALO + r;
        f4 a = {0.f, 0.f, 0.f, 0.f};
        if (gr >= 0 && gr < HGT)
            a = *(const f4*)(xbase + ((size_t)(c8 * HGT + gr)) * WID + q * 4);
        // neighbors: left lane's top 3, right lane's bottom 3 (zero at row edges)
        float l1 = __shfl_up(a.y, 1);
        float l2 = __shfl_up(a.z, 1);
        float l3 = __shfl_up(a.w, 1);
        float rr0 = __shfl_down(a.x, 1);
        float rr1 = __shfl_down(a.y, 1);
        float rr2 = __shfl_down(a.z, 1);
        if (q == 0)  { l1 = 0.f; l2 = 0.f; l3 = 0.f; }
        if (q == 15) { rr0 = 0.f; rr1 = 0.f; rr2 = 0.f; }
        f4 s;
        s.x = ((l1 + l2) + (l3 + a.x)) + ((a.y + a.z) + a.w);
        s.y = s.x - l1 + rr0;
        s.z = s.y - l2 + rr1;
        s.w = s.z - l3 + rr2;
        *(f4*)&hp[(c8 * HPR + r) * WID + q * 4] = s;
    }
    __syncthreads();

    // ---- Phase 2: vertical 7-tap + 1x1 conv (Wv) + store; 1 pixel/thread ----
    float w[NM * NC];
    #pragma unroll
    for (int i = 0; i < NM * NC; ++i) w[i] = wv_s[i];

    const int r = wave;          // 0..3
    const int c = lane;          // 0..63

    float vb[NC];
    #pragma unroll
    for (int c8 = 0; c8 < NC; ++c8) {
        float a = 0.0f;
        #pragma unroll
        for (int dr = 0; dr < 7; ++dr)
            a += hp[(c8 * HPR + r + dr) * WID + c];
        vb[c8] = a;
    }

    float* obase = out + (size_t)bg * NM * HGT * WID;
    #pragma unroll
    for (int m = 0; m < NM; ++m) {
        float o = 0.0f;
        #pragma unroll
        for (int c8 = 0; c8 < NC; ++c8)
            o += w[m * NC + c8] * vb[c8];
        obase[((size_t)m * HGT + (r0 + r)) * WID + c] = o;
    }
}

extern "C" void kernel_launch(void* const* d_in, const int* in_sizes, int n_in,
                              void* d_out, int out_size, void* d_ws, size_t ws_size,
                              hipStream_t stream) {
    const float* x  = (const float*)d_in[0];
    // d_in[1] = Wq, d_in[2] = Wk  -- dead (softmax over singleton axis == 1)
    const float* Wv = (const float*)d_in[3];
    float* out = (float*)d_out;

    dim3 grid(NTILE * NBG);   // 1024 blocks
    dim3 block(256);
    mhsa_boxsum_kernel<<<grid, block, 0, stream>>>(x, Wv, out);
}

// Round 4
// 10.417 us; speedup vs baseline: 1.9696x; 1.0119x over previous
//
#include <hip/hip_runtime.h>

// Reference collapses: softmax over singleton axis => weights == 1.
// out[b, g*M+m, h, w] = 7x7 box sum of v,  v = grouped 1x1 conv(x, Wv).
// Separable + linear: vertical 7-tap FIRST (per-thread sliding sum in regs,
// no shfl), stage vp in LDS; then horizontal 7-tap (3x ds_read_b128 + running
// sum) fused with the Wv mix, float4 stores.
//
// R4: kills 120 shfl + 224 b32 LDS reads per block of R3; LDS pipe ~2.5x less.

#define TH   8           // output rows per block
#define HALO 3
#define LR   (TH + 6)    // 14 loaded rows
#define WID  64
#define HGT  64
#define NG   8
#define NM   8
#define NC   8
#define NTILE (HGT / TH) // 8
#define NBG  64          // B*G
#define VPS  72          // vp row stride in floats: 4 zero-pad | 64 | 4 zero-pad

typedef float f4 __attribute__((ext_vector_type(4)));

__global__ __launch_bounds__(256)
void mhsa_boxsum_kernel(const float* __restrict__ x,
                        const float* __restrict__ Wv,
                        float* __restrict__ out) {
    __shared__ float vp[NC * TH * VPS];   // 8*8*72*4 = 18432 B
    __shared__ float wv_s[NM * NC];

    // bijective XCD-aware decode: all 8 tiles of a (b,g) on one XCD
    const int lb   = (int)blockIdx.x;     // 0..511
    const int xcd  = lb & 7;
    const int ix   = lb >> 3;             // 0..63
    const int bg   = xcd * 8 + (ix >> 3); // 0..63
    const int tile = ix & 7;              // 0..7
    const int r0   = tile * TH;

    const int tid  = (int)threadIdx.x;
    const int g    = bg & (NG - 1);
    if (tid < NM * NC) wv_s[tid] = Wv[g * (NM * NC) + tid];

    const float* xbase = x + (size_t)bg * NC * HGT * WID;

    if (tid < NC * 16) {
        // ---- P1 (threads 0..127): vertical 7-tap sliding sum, regs only ----
        const int c8 = tid >> 4;
        const int q  = tid & 15;          // w = 4q..4q+3
        f4 a[LR];
        #pragma unroll
        for (int j = 0; j < LR; ++j) {
            const int gr = r0 - HALO + j;
            f4 t = {0.f, 0.f, 0.f, 0.f};
            if (gr >= 0 && gr < HGT)
                t = *(const f4*)(xbase + ((size_t)(c8 * HGT + gr)) * WID + q * 4);
            a[j] = t;
        }
        f4 s = a[0];
        #pragma unroll
        for (int j = 1; j < 7; ++j) s += a[j];
        *(f4*)(&vp[(c8 * TH + 0) * VPS + 4 + q * 4]) = s;
        #pragma unroll
        for (int r = 1; r < TH; ++r) {
            s += a[r + 6] - a[r - 1];
            *(f4*)(&vp[(c8 * TH + r) * VPS + 4 + q * 4]) = s;
        }
    } else {
        // ---- threads 128..255: zero the left/right pads (128 f4 slots) ----
        const int p    = tid - 128;       // 0..127
        const int side = p & 1;
        const int r    = (p >> 1) & 7;
        const int c8   = p >> 4;
        *(f4*)(&vp[(c8 * TH + r) * VPS + side * 68]) = (f4){0.f, 0.f, 0.f, 0.f};
    }
    __syncthreads();

    // ---- P2: horizontal 7-tap running sum + Wv mix; thread = (quad-row, m-half)
    const int qr = tid & 127;
    const int mh = tid >> 7;              // 0: m 0-3, 1: m 4-7
    const int q  = qr & 15;
    const int r  = qr >> 4;               // 0..7

    f4 w0[4], w1[4];
    #pragma unroll
    for (int mi = 0; mi < 4; ++mi) {
        w0[mi] = *(const f4*)&wv_s[(mh * 4 + mi) * 8 + 0];
        w1[mi] = *(const f4*)&wv_s[(mh * 4 + mi) * 8 + 4];
    }

    f4 acc[4];
    #pragma unroll
    for (int mi = 0; mi < 4; ++mi) acc[mi] = (f4){0.f, 0.f, 0.f, 0.f};

    #pragma unroll
    for (int c8 = 0; c8 < NC; ++c8) {
        const float* row = &vp[(c8 * TH + r) * VPS + q * 4];
        f4 L = *(const f4*)(row);        // w-4..w-1 (pad-zeroed at q==0)
        f4 M = *(const f4*)(row + 4);    // w  ..w+3
        f4 R = *(const f4*)(row + 8);    // w+4..w+7 (pad-zeroed at q==15)
        const float t  = (L.y + L.z) + L.w;
        const float sM = (M.x + M.y) + (M.z + M.w);
        f4 hb;
        hb.x = t + sM;
        hb.y = hb.x - L.y + R.x;
        hb.z = hb.y - L.z + R.y;
        hb.w = hb.z - L.w + R.z;
        #pragma unroll
        for (int mi = 0; mi < 4; ++mi) {
            const float wv = (c8 < 4) ? w0[mi][c8] : w1[mi][c8 - 4];
            acc[mi] += hb * wv;
        }
    }

    float* obase = out + (size_t)bg * NM * HGT * WID;
    #pragma unroll
    for (int mi = 0; mi < 4; ++mi) {
        const int m = mh * 4 + mi;
        *(f4*)(obase + ((size_t)(m * HGT + r0 + r)) * WID + q * 4) = acc[mi];
    }
}

extern "C" void kernel_launch(void* const* d_in, const int* in_sizes, int n_in,
                              void* d_out, int out_size, void* d_ws, size_t ws_size,
                              hipStream_t stream) {
    const float* x  = (const float*)d_in[0];
    // d_in[1] = Wq, d_in[2] = Wk  -- dead (softmax over singleton axis == 1)
    const float* Wv = (const float*)d_in[3];
    float* out = (float*)d_out;

    dim3 grid(NTILE * NBG);   // 512 blocks = 2/CU, 8 waves/CU
    dim3 block(256);
    mhsa_boxsum_kernel<<<grid, block, 0, stream>>>(x, Wv, out);
}